// Round 6
// baseline (230.515 us; speedup 1.0000x reference)
//
#include <hip/hip_runtime.h>
#include <hip/hip_bf16.h>

#define N_TOK  16384   // B*H*W
#define KCODES 2048
#define CDIM   128
#define BM     32      // rows per block -> grid 512
#define TPB    256     // 4 waves, ALL compute (zero-fill moved to hipMemsetAsync)
#define NCW    4
#define CPW    (KCODES / NCW)   // 512 codes per wave
#define TPW    (CPW / 16)       // 32 tiles per wave
#define SEEDT  8       // seed tiles/wave: 4*8*16 = 512 codes seed the threshold
#define CAP    128     // candidate cap (E[cand]~7/row with 512-code seed)
#define DELTA  5.0f    // bf16 d2 error bound ~1.05; 5 is ~5x safe (validated R4)
#define ASTR   36

typedef __attribute__((ext_vector_type(8))) short bhalf8;
typedef __attribute__((ext_vector_type(4))) float facc4;

// ---- prep: codebook fp32 -> bf16 in MFMA-frag-tiled layout, + ||w||^2 ----
// element (16B) index = T*256 + kf*64 + (q*16 + r)
//   holds code (T*16+r), dims [kf*32 + q*8, +8)  == B-frag for (tile T, kf)
__global__ __launch_bounds__(256) void prep_kernel(const float* __restrict__ cb,
                                                   bhalf8* __restrict__ cbt,
                                                   float* __restrict__ wsq) {
    const int T   = blockIdx.x;
    const int tid = threadIdx.x;
    const int r   = tid >> 4;
    const int g   = tid & 15;
    const float4* src = (const float4*)(cb + ((size_t)(T * 16 + r)) * CDIM + g * 8);
    float4 a0 = src[0], a1 = src[1];

    float s = a0.x*a0.x + a0.y*a0.y + a0.z*a0.z + a0.w*a0.w
            + a1.x*a1.x + a1.y*a1.y + a1.z*a1.z + a1.w*a1.w;
    s += __shfl_xor(s, 1, 64);
    s += __shfl_xor(s, 2, 64);
    s += __shfl_xor(s, 4, 64);
    s += __shfl_xor(s, 8, 64);
    if (g == 0) wsq[T * 16 + r] = s;

    union { unsigned u[4]; bhalf8 v; } fu;
    __hip_bfloat162 h0 = __float22bfloat162_rn(make_float2(a0.x, a0.y));
    __hip_bfloat162 h1 = __float22bfloat162_rn(make_float2(a0.z, a0.w));
    __hip_bfloat162 h2 = __float22bfloat162_rn(make_float2(a1.x, a1.y));
    __hip_bfloat162 h3 = __float22bfloat162_rn(make_float2(a1.z, a1.w));
    fu.u[0] = *(unsigned*)&h0; fu.u[1] = *(unsigned*)&h1;
    fu.u[2] = *(unsigned*)&h2; fu.u[3] = *(unsigned*)&h3;
    const int kf = g >> 2, q = g & 3;
    cbt[(size_t)T * 256 + kf * 64 + q * 16 + r] = fu.v;
}

// ---- main: pure compute. BM=32, 4 waves, seed-threshold single sweep ----
__global__ __launch_bounds__(TPB, 2) void argmin_kernel(const float* __restrict__ x,
                                                        const float* __restrict__ cb,
                                                        const bhalf8* __restrict__ cbt,
                                                        const float* __restrict__ wsqg,
                                                        float* __restrict__ enc,
                                                        float* __restrict__ quant) {
    __shared__ float As[CDIM][ASTR];     // 18.4 KB exact fp32 x, c-major
    __shared__ float wsqs[KCODES];       // 8 KB
    __shared__ float redvw[NCW][BM];     // 512 B
    __shared__ float rowthr[BM];
    __shared__ int   cnt[BM];
    __shared__ int   candk[BM][CAP];     // 16 KB
    __shared__ int   rowidx[BM];

    const int tid  = threadIdx.x;
    const int lane = tid & 63;
    const int w    = tid >> 6;           // 0..3
    const int q    = lane >> 4;
    const int r    = lane & 15;
    const int n0   = blockIdx.x * BM;    // 1024 % 32 == 0: single batch
    const int b    = n0 >> 10;
    const int hw0  = n0 & 1023;

    // ---- stage As (coalesced float4 over hw), wsqs, init cnt
    {
        int m4 = (tid & 7) << 2;         // 0..28
        int c0 = tid >> 3;               // 0..31
        #pragma unroll
        for (int i = 0; i < 4; i++) {
            int c = c0 + 32 * i;
            float4 v = *(const float4*)(x + (((size_t)(b * CDIM + c)) << 10) + hw0 + m4);
            *(float4*)(&As[c][m4]) = v;
        }
    }
    #pragma unroll
    for (int i = 0; i < KCODES / TPB; i++) wsqs[i * TPB + tid] = wsqg[i * TPB + tid];
    if (tid < BM) cnt[tid] = 0;
    __syncthreads();

    // ---- A-frags in registers: 2 row-tiles (32 rows), layout verified R3/R4
    bhalf8 af[2][4];
    #pragma unroll
    for (int rt = 0; rt < 2; rt++) {
        int m = rt * 16 + r;
        #pragma unroll
        for (int kf = 0; kf < 4; kf++) {
            union { unsigned u[4]; bhalf8 v; } fu;
            #pragma unroll
            for (int p = 0; p < 4; p++) {
                int k = kf * 32 + q * 8 + 2 * p;
                __hip_bfloat162 h = __float22bfloat162_rn(make_float2(As[k][m], As[k + 1][m]));
                fu.u[p] = *(unsigned*)&h;
            }
            af[rt][kf] = fu.v;
        }
    }

    const int    cw  = w * CPW;                       // wave's code base
    const size_t tb0 = (size_t)(cw >> 4) * 256;       // its first tile's frag base

    // =============== seed phase: tiles 0..SEEDT-1 -> per-row seed min =======
    {
        float rmin[8];
        #pragma unroll
        for (int t = 0; t < 8; t++) rmin[t] = 3.0e38f;

        for (int t = 0; t < SEEDT; t++) {
            bhalf8 bt[4];
            #pragma unroll
            for (int kf = 0; kf < 4; kf++) bt[kf] = cbt[tb0 + (size_t)t * 256 + kf * 64 + lane];
            facc4 acc[2];
            #pragma unroll
            for (int rt = 0; rt < 2; rt++) acc[rt] = (facc4){0.f, 0.f, 0.f, 0.f};
            #pragma unroll
            for (int kf = 0; kf < 4; kf++)
                #pragma unroll
                for (int rt = 0; rt < 2; rt++)
                    acc[rt] = __builtin_amdgcn_mfma_f32_16x16x32_bf16(af[rt][kf], bt[kf], acc[rt], 0, 0, 0);
            float wv = wsqs[cw + t * 16 + r];
            #pragma unroll
            for (int rt = 0; rt < 2; rt++)
                #pragma unroll
                for (int i = 0; i < 4; i++)
                    rmin[rt * 4 + i] = fminf(rmin[rt * 4 + i], fmaf(-2.f, acc[rt][i], wv));
        }
        #pragma unroll
        for (int t = 0; t < 8; t++) {
            float v = rmin[t];
            v = fminf(v, __shfl_xor(v, 1, 64));
            v = fminf(v, __shfl_xor(v, 2, 64));
            v = fminf(v, __shfl_xor(v, 4, 64));
            v = fminf(v, __shfl_xor(v, 8, 64));
            if (r == 0) redvw[w][(t >> 2) * 16 + q * 4 + (t & 3)] = v;
        }
    }
    __syncthreads();
    if (tid < BM) {
        float mv = fminf(fminf(redvw[0][tid], redvw[1][tid]),
                         fminf(redvw[2][tid], redvw[3][tid]));
        rowthr[tid] = mv + DELTA;
    }
    __syncthreads();

    // =============== main sweep: all 32 tiles, harvest candidates ===========
    {
        float thr[8];
        #pragma unroll
        for (int t = 0; t < 8; t++) thr[t] = rowthr[(t >> 2) * 16 + q * 4 + (t & 3)];

        bhalf8 bcur[4], bnxt[4];
        #pragma unroll
        for (int kf = 0; kf < 4; kf++) bcur[kf] = cbt[tb0 + kf * 64 + lane];
        #pragma unroll
        for (int kf = 0; kf < 4; kf++) bnxt[kf] = cbt[tb0 + 256 + kf * 64 + lane];

        for (int t = 0; t < TPW; t++) {
            bhalf8 bn2[4];
            if (t + 2 < TPW) {
                size_t tb = tb0 + (size_t)(t + 2) * 256;
                #pragma unroll
                for (int kf = 0; kf < 4; kf++) bn2[kf] = cbt[tb + kf * 64 + lane];
            }
            facc4 acc[2];
            #pragma unroll
            for (int rt = 0; rt < 2; rt++) acc[rt] = (facc4){0.f, 0.f, 0.f, 0.f};
            #pragma unroll
            for (int kf = 0; kf < 4; kf++)
                #pragma unroll
                for (int rt = 0; rt < 2; rt++)
                    acc[rt] = __builtin_amdgcn_mfma_f32_16x16x32_bf16(af[rt][kf], bcur[kf], acc[rt], 0, 0, 0);
            float wv = wsqs[cw + t * 16 + r];
            #pragma unroll
            for (int rt = 0; rt < 2; rt++)
                #pragma unroll
                for (int i = 0; i < 4; i++) {
                    float d = fmaf(-2.f, acc[rt][i], wv);
                    if (d <= thr[rt * 4 + i]) {
                        int row = rt * 16 + q * 4 + i;
                        int p = atomicAdd(&cnt[row], 1);
                        if (p < CAP) candk[row][p] = cw + t * 16 + r;
                    }
                }
            #pragma unroll
            for (int kf = 0; kf < 4; kf++) { bcur[kf] = bnxt[kf]; bnxt[kf] = bn2[kf]; }
        }
    }
    __syncthreads();

    // =============== exact fp32 rescore (4 waves, 8 rows each) ==============
    for (int m = 8 * w; m < 8 * w + 8; m++) {
        int c = cnt[m];
        float bv = 3.0e38f; int bk = 0x7fffffff;
        if (c > CAP) {
            // safety net (statistically ~never): exact full scan, lanes over codes
            for (int k = lane; k < KCODES; k += 64) {
                float s = 0.f;
                for (int cd = 0; cd < CDIM; cd++)
                    s = fmaf(As[cd][m], cb[(size_t)k * CDIM + cd], s);
                float d = fmaf(-2.f, s, wsqs[k]);
                if (d < bv || (d == bv && k < bk)) { bv = d; bk = k; }
            }
            #pragma unroll
            for (int off = 1; off <= 32; off <<= 1) {
                float ov = __shfl_xor(bv, off, 64);
                int   ok = __shfl_xor(bk, off, 64);
                if (ov < bv || (ov == bv && ok < bk)) { bv = ov; bk = ok; }
            }
        } else {
            for (int t = 0; t < c; t++) {
                int k = candk[m][t];
                float x0 = As[lane][m], x1 = As[lane + 64][m];
                float c0 = cb[(size_t)k * CDIM + lane];
                float c1 = cb[(size_t)k * CDIM + 64 + lane];
                float s = x0 * c0 + x1 * c1;
                #pragma unroll
                for (int off = 1; off <= 32; off <<= 1) s += __shfl_xor(s, off, 64);
                float d = fmaf(-2.f, s, wsqs[k]);
                if (d < bv || (d == bv && k < bk)) { bv = d; bk = k; }
            }
        }
        if (bk == 0x7fffffff) bk = 0;   // unreachable guard
        if (lane == 0) rowidx[m] = bk;
    }
    __syncthreads();

    // ---- ones (zeros pre-written by hipMemsetAsync) + quantized NCHW
    if (tid < BM) enc[(size_t)(n0 + tid) * KCODES + rowidx[tid]] = 1.0f;

    #pragma unroll
    for (int i = tid; i < BM * CDIM / 4; i += TPB) {
        int c  = i >> 3;                 // 0..127
        int hq = (i & 7) << 2;           // 0..28
        float4 v;
        v.x = cb[(size_t)rowidx[hq + 0] * CDIM + c];
        v.y = cb[(size_t)rowidx[hq + 1] * CDIM + c];
        v.z = cb[(size_t)rowidx[hq + 2] * CDIM + c];
        v.w = cb[(size_t)rowidx[hq + 3] * CDIM + c];
        *(float4*)(quant + (((size_t)(b * CDIM + c)) << 10) + hw0 + hq) = v;
    }
}

extern "C" void kernel_launch(void* const* d_in, const int* in_sizes, int n_in,
                              void* d_out, int out_size, void* d_ws, size_t ws_size,
                              hipStream_t stream) {
    const float* x  = (const float*)d_in[0];   // [16,128,32,32] f32
    const float* cb = (const float*)d_in[1];   // [2048,128] f32
    float* out = (float*)d_out;                // encodings [N,K] then quantized

    bhalf8* cbt  = (bhalf8*)d_ws;                      // 512 KB tiled bf16
    float*  wsqp = (float*)((char*)d_ws + 512 * 1024); // 8 KB

    // zero the one-hot encodings with the runtime's fill path (~6.3 TB/s)
    hipMemsetAsync(out, 0, (size_t)N_TOK * KCODES * sizeof(float), stream);
    prep_kernel<<<KCODES / 16, 256, 0, stream>>>(cb, cbt, wsqp);
    argmin_kernel<<<N_TOK / BM, TPB, 0, stream>>>(x, cb, cbt, wsqp,
                                                  out, out + (size_t)N_TOK * KCODES);
}

// Round 7
// 199.126 us; speedup vs baseline: 1.1576x; 1.1576x over previous
//
#include <hip/hip_runtime.h>
#include <hip/hip_bf16.h>

#define N_TOK  16384   // B*H*W
#define KCODES 2048
#define CDIM   128
#define BM     16      // rows per block -> grid 1024 = 4 blocks/CU (TLP fix)
#define TPB    256     // 4 waves
#define NCW    4
#define CPW    (KCODES / NCW)   // 512 codes per wave
#define TPW    (CPW / 16)       // 32 tiles per wave
#define SEEDT  8       // seed tiles/wave: 4*8*16 = 512 codes seed the threshold
#define CAP    64      // candidate cap (E[cand]~3/row with 512-code seed)
#define DELTA  5.0f    // bf16 d2 error bound ~1.05; 5 is ~5x safe (validated R4)
#define ASTR   20      // 16 rows + 4 pad (keeps float4 stores 16B-aligned)

typedef __attribute__((ext_vector_type(8))) short bhalf8;
typedef __attribute__((ext_vector_type(4))) float facc4;

// ---- prep: codebook fp32 -> bf16 in MFMA-frag-tiled layout, + ||w||^2 ----
// element (16B) index = T*256 + kf*64 + (q*16 + r)
//   holds code (T*16+r), dims [kf*32 + q*8, +8)  == B-frag for (tile T, kf)
__global__ __launch_bounds__(256) void prep_kernel(const float* __restrict__ cb,
                                                   bhalf8* __restrict__ cbt,
                                                   float* __restrict__ wsq) {
    const int T   = blockIdx.x;
    const int tid = threadIdx.x;
    const int r   = tid >> 4;
    const int g   = tid & 15;
    const float4* src = (const float4*)(cb + ((size_t)(T * 16 + r)) * CDIM + g * 8);
    float4 a0 = src[0], a1 = src[1];

    float s = a0.x*a0.x + a0.y*a0.y + a0.z*a0.z + a0.w*a0.w
            + a1.x*a1.x + a1.y*a1.y + a1.z*a1.z + a1.w*a1.w;
    s += __shfl_xor(s, 1, 64);
    s += __shfl_xor(s, 2, 64);
    s += __shfl_xor(s, 4, 64);
    s += __shfl_xor(s, 8, 64);
    if (g == 0) wsq[T * 16 + r] = s;

    union { unsigned u[4]; bhalf8 v; } fu;
    __hip_bfloat162 h0 = __float22bfloat162_rn(make_float2(a0.x, a0.y));
    __hip_bfloat162 h1 = __float22bfloat162_rn(make_float2(a0.z, a0.w));
    __hip_bfloat162 h2 = __float22bfloat162_rn(make_float2(a1.x, a1.y));
    __hip_bfloat162 h3 = __float22bfloat162_rn(make_float2(a1.z, a1.w));
    fu.u[0] = *(unsigned*)&h0; fu.u[1] = *(unsigned*)&h1;
    fu.u[2] = *(unsigned*)&h2; fu.u[3] = *(unsigned*)&h3;
    const int kf = g >> 2, q = g & 3;
    cbt[(size_t)T * 256 + kf * 64 + q * 16 + r] = fu.v;
}

// ---- main: BM=16, grid 1024, 16 waves/CU; fill folded into sweep ----
__global__ __launch_bounds__(TPB, 4) void argmin_kernel(const float* __restrict__ x,
                                                        const float* __restrict__ cb,
                                                        const bhalf8* __restrict__ cbt,
                                                        const float* __restrict__ wsqg,
                                                        float* __restrict__ enc,
                                                        float* __restrict__ quant) {
    __shared__ float As[CDIM][ASTR];     // 10 KB exact fp32 x, c-major
    __shared__ float wsqs[KCODES];       // 8 KB
    __shared__ float redvw[NCW][BM];     // 256 B
    __shared__ float rowthr[BM];
    __shared__ int   cnt[BM];
    __shared__ int   candk[BM][CAP];     // 4 KB
    __shared__ int   rowidx[BM];

    const int tid  = threadIdx.x;
    const int lane = tid & 63;
    const int w    = tid >> 6;           // 0..3
    const int q    = lane >> 4;
    const int r    = lane & 15;
    const int n0   = blockIdx.x * BM;    // 1024 % 16 == 0: single batch
    const int b    = n0 >> 10;
    const int hw0  = n0 & 1023;
    const float4 z4 = {0.f, 0.f, 0.f, 0.f};

    // ---- stage As (coalesced float4 over hw), wsqs, init cnt
    {
        int m4 = (tid & 3) << 2;         // 0,4,8,12
        int c0 = tid >> 2;               // 0..63
        #pragma unroll
        for (int i = 0; i < 2; i++) {
            int c = c0 + 64 * i;
            float4 v = *(const float4*)(x + (((size_t)(b * CDIM + c)) << 10) + hw0 + m4);
            *(float4*)(&As[c][m4]) = v;
        }
    }
    #pragma unroll
    for (int i = 0; i < KCODES / TPB; i++) wsqs[i * TPB + tid] = wsqg[i * TPB + tid];
    if (tid < BM) cnt[tid] = 0;
    __syncthreads();

    // ---- A-frags in registers: 1 row-tile (16 rows), layout verified R3/R4
    bhalf8 af[4];
    {
        int m = r;
        #pragma unroll
        for (int kf = 0; kf < 4; kf++) {
            union { unsigned u[4]; bhalf8 v; } fu;
            #pragma unroll
            for (int p = 0; p < 4; p++) {
                int k = kf * 32 + q * 8 + 2 * p;
                __hip_bfloat162 h = __float22bfloat162_rn(make_float2(As[k][m], As[k + 1][m]));
                fu.u[p] = *(unsigned*)&h;
            }
            af[kf] = fu.v;
        }
    }

    const int    cw  = w * CPW;                       // wave's code base
    const size_t tb0 = (size_t)(cw >> 4) * 256;       // its first tile's frag base

    // =============== seed phase: tiles 0..SEEDT-1 -> per-row seed min =======
    {
        float rmin[4];
        #pragma unroll
        for (int t = 0; t < 4; t++) rmin[t] = 3.0e38f;

        for (int t = 0; t < SEEDT; t++) {
            bhalf8 bt[4];
            #pragma unroll
            for (int kf = 0; kf < 4; kf++) bt[kf] = cbt[tb0 + (size_t)t * 256 + kf * 64 + lane];
            facc4 acc = (facc4){0.f, 0.f, 0.f, 0.f};
            #pragma unroll
            for (int kf = 0; kf < 4; kf++)
                acc = __builtin_amdgcn_mfma_f32_16x16x32_bf16(af[kf], bt[kf], acc, 0, 0, 0);
            float wv = wsqs[cw + t * 16 + r];
            #pragma unroll
            for (int i = 0; i < 4; i++)
                rmin[i] = fminf(rmin[i], fmaf(-2.f, acc[i], wv));
        }
        #pragma unroll
        for (int t = 0; t < 4; t++) {
            float v = rmin[t];
            v = fminf(v, __shfl_xor(v, 1, 64));
            v = fminf(v, __shfl_xor(v, 2, 64));
            v = fminf(v, __shfl_xor(v, 4, 64));
            v = fminf(v, __shfl_xor(v, 8, 64));
            if (r == 0) redvw[w][q * 4 + t] = v;
        }
    }
    __syncthreads();
    if (tid < BM) {
        float mv = fminf(fminf(redvw[0][tid], redvw[1][tid]),
                         fminf(redvw[2][tid], redvw[3][tid]));
        rowthr[tid] = mv + DELTA;
    }
    __syncthreads();

    // =============== main sweep: 32 tiles; harvest + folded enc zero-fill ===
    {
        float thr[4];
        #pragma unroll
        for (int t = 0; t < 4; t++) thr[t] = rowthr[q * 4 + t];

        float4* fdst = (float4*)(enc + (size_t)n0 * KCODES);  // 8192 float4

        bhalf8 bcur[4], bnxt[4];
        #pragma unroll
        for (int kf = 0; kf < 4; kf++) bcur[kf] = cbt[tb0 + kf * 64 + lane];
        #pragma unroll
        for (int kf = 0; kf < 4; kf++) bnxt[kf] = cbt[tb0 + 256 + kf * 64 + lane];

        for (int t = 0; t < TPW; t++) {
            bhalf8 bn2[4];
            if (t + 2 < TPW) {
                size_t tb = tb0 + (size_t)(t + 2) * 256;
                #pragma unroll
                for (int kf = 0; kf < 4; kf++) bn2[kf] = cbt[tb + kf * 64 + lane];
            }
            fdst[t * TPB + tid] = z4;    // 32 iters x 4 KB = block's 16 enc rows
            facc4 acc = (facc4){0.f, 0.f, 0.f, 0.f};
            #pragma unroll
            for (int kf = 0; kf < 4; kf++)
                acc = __builtin_amdgcn_mfma_f32_16x16x32_bf16(af[kf], bcur[kf], acc, 0, 0, 0);
            float wv = wsqs[cw + t * 16 + r];
            #pragma unroll
            for (int i = 0; i < 4; i++) {
                float d = fmaf(-2.f, acc[i], wv);
                if (d <= thr[i]) {
                    int row = q * 4 + i;
                    int p = atomicAdd(&cnt[row], 1);
                    if (p < CAP) candk[row][p] = cw + t * 16 + r;
                }
            }
            #pragma unroll
            for (int kf = 0; kf < 4; kf++) { bcur[kf] = bnxt[kf]; bnxt[kf] = bn2[kf]; }
        }
    }
    __syncthreads();

    // =============== exact fp32 rescore (4 waves, 4 rows each) ==============
    for (int m = 4 * w; m < 4 * w + 4; m++) {
        int c = cnt[m];
        float bv = 3.0e38f; int bk = 0x7fffffff;
        if (c > CAP) {
            // safety net (statistically ~never): exact full scan, lanes over codes
            for (int k = lane; k < KCODES; k += 64) {
                float s = 0.f;
                for (int cd = 0; cd < CDIM; cd++)
                    s = fmaf(As[cd][m], cb[(size_t)k * CDIM + cd], s);
                float d = fmaf(-2.f, s, wsqs[k]);
                if (d < bv || (d == bv && k < bk)) { bv = d; bk = k; }
            }
            #pragma unroll
            for (int off = 1; off <= 32; off <<= 1) {
                float ov = __shfl_xor(bv, off, 64);
                int   ok = __shfl_xor(bk, off, 64);
                if (ov < bv || (ov == bv && ok < bk)) { bv = ov; bk = ok; }
            }
        } else {
            for (int t = 0; t < c; t++) {
                int k = candk[m][t];
                float x0 = As[lane][m], x1 = As[lane + 64][m];
                float c0 = cb[(size_t)k * CDIM + lane];
                float c1 = cb[(size_t)k * CDIM + 64 + lane];
                float s = x0 * c0 + x1 * c1;
                #pragma unroll
                for (int off = 1; off <= 32; off <<= 1) s += __shfl_xor(s, off, 64);
                float d = fmaf(-2.f, s, wsqs[k]);
                if (d < bv || (d == bv && k < bk)) { bv = d; bk = k; }
            }
        }
        if (bk == 0x7fffffff) bk = 0;   // unreachable guard
        if (lane == 0) rowidx[m] = bk;
    }
    __syncthreads();

    // ---- ones (zeros drained by barriers above) + quantized NCHW
    if (tid < BM) enc[(size_t)(n0 + tid) * KCODES + rowidx[tid]] = 1.0f;

    #pragma unroll
    for (int i = tid; i < BM * CDIM / 4; i += TPB) {
        int c  = i >> 2;                 // 0..127
        int hq = (i & 3) << 2;           // 0,4,8,12
        float4 v;
        v.x = cb[(size_t)rowidx[hq + 0] * CDIM + c];
        v.y = cb[(size_t)rowidx[hq + 1] * CDIM + c];
        v.z = cb[(size_t)rowidx[hq + 2] * CDIM + c];
        v.w = cb[(size_t)rowidx[hq + 3] * CDIM + c];
        *(float4*)(quant + (((size_t)(b * CDIM + c)) << 10) + hw0 + hq) = v;
    }
}

extern "C" void kernel_launch(void* const* d_in, const int* in_sizes, int n_in,
                              void* d_out, int out_size, void* d_ws, size_t ws_size,
                              hipStream_t stream) {
    const float* x  = (const float*)d_in[0];   // [16,128,32,32] f32
    const float* cb = (const float*)d_in[1];   // [2048,128] f32
    float* out = (float*)d_out;                // encodings [N,K] then quantized

    bhalf8* cbt  = (bhalf8*)d_ws;                      // 512 KB tiled bf16
    float*  wsqp = (float*)((char*)d_ws + 512 * 1024); // 8 KB

    prep_kernel<<<KCODES / 16, 256, 0, stream>>>(cb, cbt, wsqp);
    argmin_kernel<<<N_TOK / BM, TPB, 0, stream>>>(x, cb, cbt, wsqp,
                                                  out, out + (size_t)N_TOK * KCODES);
}